// Round 7
// baseline (161.041 us; speedup 1.0000x reference)
//
#include <hip/hip_runtime.h>
#include <math.h>

#define B_ 2
#define T_ 2048
#define D_ 1024
#define H_ 16
#define HD_ 64
#define EPS_ 1.1920929e-07f
#define VE_SCALE_ 2.0f
#define QN_ 3200   // 3072 qkv cols + 16 attn-gate + 16 ve-gate + 96 pad

typedef __bf16 bf16_t;
typedef __bf16 bf16x4 __attribute__((ext_vector_type(4)));
typedef __bf16 bf16x8 __attribute__((ext_vector_type(8)));
typedef float f32x4 __attribute__((ext_vector_type(4)));

__device__ const f32x4 F4ZERO = {0.f, 0.f, 0.f, 0.f};

typedef __attribute__((address_space(1))) const void gvoid_t;
typedef __attribute__((address_space(3))) void lvoid_t;

__device__ __forceinline__ void gl_lds16(const bf16_t* g, bf16_t* l) {
  // async global->LDS, 16B/lane; LDS dest = wave-uniform base + lane*16
  __builtin_amdgcn_global_load_lds((gvoid_t*)g, (lvoid_t*)l, 16, 0, 0);
}

// ---------------- cast f32 -> bf16 (vectorized, 4/thread) ----------------
__global__ __launch_bounds__(256) void cast_bf16(
    const float* __restrict__ in, bf16_t* __restrict__ out, int n4)
{
  const int i = blockIdx.x * 256 + threadIdx.x;
  if (i >= n4) return;
  const float4 v = ((const float4*)in)[i];
  bf16x4 o = {(bf16_t)v.x, (bf16_t)v.y, (bf16_t)v.z, (bf16_t)v.w};
  ((bf16x4*)out)[i] = o;
}

// cast the full qkvo weight (4M f32): rows [0,3072) -> wq, [3072,4096) -> wo
__global__ __launch_bounds__(256) void cast_qkvo(
    const float* __restrict__ in, bf16_t* __restrict__ wq,
    bf16_t* __restrict__ wo, int n4, int nsplit4)
{
  const int i = blockIdx.x * 256 + threadIdx.x;
  if (i >= n4) return;
  const float4 v = ((const float4*)in)[i];
  bf16x4 o = {(bf16_t)v.x, (bf16_t)v.y, (bf16_t)v.z, (bf16_t)v.w};
  if (i < nsplit4) ((bf16x4*)wq)[i] = o;
  else             ((bf16x4*)wo)[i - nsplit4] = o;
}

// ---------------- bf16 MFMA GEMM (m97/r4 structure): C = scale * A @ W^T --
// 128x128 tile, BK=32, 4 waves (2x2 of 64x64), global_load_lds width-16
// staging into linear LDS [128][32], 2-barrier K-loop, 16 MFMA/wave/K-step.
// Cols >= n_scaled skip the lambda scale (gate columns). out_bf: bf16 C.
__global__ __launch_bounds__(256) void gemm_bf16(
    const bf16_t* __restrict__ A, const bf16_t* __restrict__ W,
    void* __restrict__ Cout, int M, int N, int K,
    const float* __restrict__ lam, int li, int n_scaled, int out_bf)
{
  const float scale = lam[li];
  __shared__ bf16_t As[128][32];
  __shared__ bf16_t Bs[128][32];
  const int tid = threadIdx.x;
  const int lane = tid & 63, w = tid >> 6;
  const int lr = lane & 15, lg = lane >> 4;
  const int wr = w >> 1, wc = w & 1;
  const int row0 = blockIdx.y * 128, col0 = blockIdx.x * 128;
  // staging: wave w covers tile rows [w*32, +32); each gl_lds covers 16 rows
  const int srow = w * 32 + (lane >> 2);
  const int scol = (lane & 3) * 8;
  const bf16_t* Ag = A + (size_t)(row0 + srow) * K + scol;
  const bf16_t* Wg = W + (size_t)(col0 + srow) * K + scol;
  bf16_t* AsB0 = &As[w * 32][0];
  bf16_t* AsB1 = &As[w * 32 + 16][0];
  bf16_t* BsB0 = &Bs[w * 32][0];
  bf16_t* BsB1 = &Bs[w * 32 + 16][0];
  const size_t r16 = (size_t)16 * K;

  f32x4 acc[4][4];
#pragma unroll
  for (int i = 0; i < 4; ++i)
#pragma unroll
    for (int j = 0; j < 4; ++j) acc[i][j] = F4ZERO;

  for (int k0 = 0; k0 < K; k0 += 32) {
    __syncthreads();  // previous K-tile fully consumed
    gl_lds16(Ag + k0, AsB0);
    gl_lds16(Ag + r16 + k0, AsB1);
    gl_lds16(Wg + k0, BsB0);
    gl_lds16(Wg + r16 + k0, BsB1);
    __syncthreads();  // drains vmcnt(0): staged data visible

    bf16x8 af[4], bfr[4];
#pragma unroll
    for (int fm = 0; fm < 4; ++fm)
      af[fm] = *(const bf16x8*)&As[wr * 64 + fm * 16 + lr][lg * 8];
#pragma unroll
    for (int fn = 0; fn < 4; ++fn)
      bfr[fn] = *(const bf16x8*)&Bs[wc * 64 + fn * 16 + lr][lg * 8];
#pragma unroll
    for (int fm = 0; fm < 4; ++fm)
#pragma unroll
      for (int fn = 0; fn < 4; ++fn)
        acc[fm][fn] = __builtin_amdgcn_mfma_f32_16x16x32_bf16(
            af[fm], bfr[fn], acc[fm][fn], 0, 0, 0);
  }
  // epilogue: C/D layout col=lane&15, row=(lane>>4)*4+reg  [m89]
#pragma unroll
  for (int fm = 0; fm < 4; ++fm)
#pragma unroll
    for (int fn = 0; fn < 4; ++fn)
#pragma unroll
      for (int r = 0; r < 4; ++r) {
        const int row = row0 + wr * 64 + fm * 16 + lg * 4 + r;
        const int col = col0 + wc * 64 + fn * 16 + lr;
        const float v = acc[fm][fn][r] * ((col < n_scaled) ? scale : 1.f);
        if (out_bf) ((bf16_t*)Cout)[(size_t)row * N + col] = (bf16_t)v;
        else        ((float*)Cout)[(size_t)row * N + col] = v;
      }
}

// -------- rmsnorm + rotary + v-augment + gate sigmoids, bf16 out --------
// qkv_b is bf16 (B*T, QN_): cols [0,3072) = qkv, [3072,3088) = attn-gate
// scores, [3088,3104) = ve-gate scores (both unscaled by lambda).
__global__ __launch_bounds__(256) void post_kernel(
    const bf16_t* __restrict__ qkv_b, const float* __restrict__ ve,
    const float* __restrict__ cosb, const float* __restrict__ sinb,
    bf16_t* __restrict__ q_bf, bf16_t* __restrict__ k_bf,
    bf16_t* __restrict__ v_bf, float* __restrict__ attn_gate)
{
  const int wid = (blockIdx.x * blockDim.x + threadIdx.x) >> 6;
  const int lane = threadIdx.x & 63;
  const int h = wid & (H_ - 1);
  const int t = (wid >> 4) & (T_ - 1);
  const int b = wid >> 15;
  const size_t row = (size_t)(b * T_ + t) * QN_;
  const float qraw = (float)qkv_b[row + h * HD_ + lane];
  const float kraw = (float)qkv_b[row + D_ + h * HD_ + lane];
  const float vraw = (float)qkv_b[row + 2 * D_ + h * HD_ + lane];
  const float c = cosb[t * (HD_ / 2) + (lane & 31)];
  const float s = sinb[t * (HD_ / 2) + (lane & 31)];

  float ssq = qraw * qraw;
  float ssk = kraw * kraw;
#pragma unroll
  for (int off = 32; off > 0; off >>= 1) {
    ssq += __shfl_xor(ssq, off);
    ssk += __shfl_xor(ssk, off);
  }
  const float qn = qraw * rsqrtf(ssq * (1.f / 64.f) + EPS_);
  const float kn = kraw * rsqrtf(ssk * (1.f / 64.f) + EPS_);
  const float qpartner = __shfl_xor(qn, 32);
  const float kpartner = __shfl_xor(kn, 32);
  const float qo = (lane < 32) ? fmaf(qn, c, qpartner * s)
                               : fmaf(qn, c, -qpartner * s);
  const float ko = (lane < 32) ? fmaf(kn, c, kpartner * s)
                               : fmaf(kn, c, -kpartner * s);
  const int bh = b * H_ + h;
  const size_t oidx = ((size_t)bh * T_ + t) * HD_ + lane;
  q_bf[oidx] = (bf16_t)qo;
  k_bf[oidx] = (bf16_t)ko;
  // gate scores (broadcast bf16 reads)
  const float gv = VE_SCALE_ / (1.f + __expf(-(float)qkv_b[row + 3088 + h]));
  const float vv = fmaf(gv, ve[(size_t)(b * T_ + t) * D_ + h * HD_ + lane], vraw);
  v_bf[oidx] = (bf16_t)vv;
  if (lane == 0)
    attn_gate[(b * T_ + t) * H_ + h] =
        1.f / (1.f + __expf(-(float)qkv_b[row + 3072 + h]));
}

// ---------------- MFMA flash attention, doc-block-diagonal ----------------
// Grid (32 q-tiles, 32 bh); block = 4 waves, wave w owns q-rows w*16..+16.
// docs sorted => q-tile qt only attends kt in [ktlo, qt].
__global__ __launch_bounds__(256) void attn_mfma(
    const bf16_t* __restrict__ q_buf, const bf16_t* __restrict__ k_tmp,
    const bf16_t* __restrict__ v_buf, const float* __restrict__ attn_gate,
    const int* __restrict__ docs, const float* __restrict__ scale_ptr,
    bf16_t* __restrict__ y_buf)
{
  const int qt = blockIdx.x, bh = blockIdx.y;
  const int b = bh >> 4, h = bh & 15;
  const int tid = threadIdx.x;
  const int w = tid >> 6, lane = tid & 63;
  const int lr = lane & 15, lg = lane >> 4;
  const float scale = scale_ptr[0];
  __shared__ bf16_t Ks[64][72];
  __shared__ bf16_t Vt[64][72];
  __shared__ bf16_t Ps[64][72];
  __shared__ int dk[64];

  // doc-range lower bound for this q-tile (docs sorted; lane<=qt<=31 bounds idx)
  const int dlo = docs[qt * 64];
  const unsigned long long bal =
      __ballot((lane <= qt) && (docs[lane * 64 + 63] >= dlo));
  const int ktlo = __ffsll(bal) - 1;

  // Q a-frags hoisted (A-frag: row = lane&15, k = (lane>>4)*8+j)
  const bf16_t* qp = q_buf + ((size_t)bh * T_ + qt * 64 + w * 16 + lr) * HD_;
  const bf16x8 aq0 = *(const bf16x8*)(qp + lg * 8);
  const bf16x8 aq1 = *(const bf16x8*)(qp + 32 + lg * 8);
  int qpos_r[4], docq_r[4];
#pragma unroll
  for (int r = 0; r < 4; ++r) {
    qpos_r[r] = qt * 64 + w * 16 + lg * 4 + r;
    docq_r[r] = docs[qpos_r[r]];
  }
  f32x4 acc[4];
#pragma unroll
  for (int fn = 0; fn < 4; ++fn) acc[fn] = F4ZERO;
  float m[4] = {-1e30f, -1e30f, -1e30f, -1e30f};
  float l[4] = {0.f, 0.f, 0.f, 0.f};

#pragma unroll 1
  for (int kt = ktlo; kt <= qt; ++kt) {
    __syncthreads();
#pragma unroll
    for (int i = 0; i < 2; ++i) {
      const int idx = i * 256 + tid;
      // K staging (fused key-offset: channels [16,32)|[48,64) from t-1)
      const int krow = idx >> 3;
      const int c8 = (idx & 7) << 3;
      const int gk = kt * 64 + krow;
      const int gks = (((c8 & 16) != 0) && gk > 0) ? gk - 1 : gk;
      *(bf16x8*)&Ks[krow][c8] =
          *(const bf16x8*)(k_tmp + ((size_t)bh * T_ + gks) * HD_ + c8);
      // V transpose staging
      const int kpos = idx & 63;
      const int d0 = (idx >> 6) << 3;
      const bf16x8 vv =
          *(const bf16x8*)(v_buf + ((size_t)bh * T_ + kt * 64 + kpos) * HD_ + d0);
#pragma unroll
      for (int j = 0; j < 8; ++j) Vt[d0 + j][kpos] = vv[j];
    }
    if (tid < 64) dk[tid] = docs[kt * 64 + tid];
    __syncthreads();

    // S = Q K^T  (B-frag: col = lane&15 = kpos, k = d contiguous)
    f32x4 s[4];
    __builtin_amdgcn_s_setprio(1);
#pragma unroll
    for (int fn = 0; fn < 4; ++fn) {
      const bf16x8 bk0 = *(const bf16x8*)&Ks[fn * 16 + lr][lg * 8];
      const bf16x8 bk1 = *(const bf16x8*)&Ks[fn * 16 + lr][32 + lg * 8];
      f32x4 z = F4ZERO;
      z = __builtin_amdgcn_mfma_f32_16x16x32_bf16(aq0, bk0, z, 0, 0, 0);
      s[fn] = __builtin_amdgcn_mfma_f32_16x16x32_bf16(aq1, bk1, z, 0, 0, 0);
    }
    __builtin_amdgcn_s_setprio(0);
    // mask + scale (lane holds rows lg*4+r, col fn*16+lr of the 64x64 S)
    const bool strict = (kt < qt);
#pragma unroll
    for (int fn = 0; fn < 4; ++fn) {
      const int kd = dk[fn * 16 + lr];
      const int kp = kt * 64 + fn * 16 + lr;
#pragma unroll
      for (int r = 0; r < 4; ++r) {
        const bool valid = (kd == docq_r[r]) && (strict || kp <= qpos_r[r]);
        s[fn][r] = valid ? s[fn][r] * scale : -3.0e38f;
      }
    }
    // online softmax (row reduce across 16-lane col group) + P write
#pragma unroll
    for (int r = 0; r < 4; ++r) {
      float cm = fmaxf(fmaxf(s[0][r], s[1][r]), fmaxf(s[2][r], s[3][r]));
      cm = fmaxf(cm, __shfl_xor(cm, 1));
      cm = fmaxf(cm, __shfl_xor(cm, 2));
      cm = fmaxf(cm, __shfl_xor(cm, 4));
      cm = fmaxf(cm, __shfl_xor(cm, 8));
      const float mn = fmaxf(m[r], cm);
      const float sc = __expf(m[r] - mn);
      m[r] = mn;
      const float p0 = __expf(s[0][r] - mn);
      const float p1 = __expf(s[1][r] - mn);
      const float p2 = __expf(s[2][r] - mn);
      const float p3 = __expf(s[3][r] - mn);
      float ps = (p0 + p1) + (p2 + p3);
      ps += __shfl_xor(ps, 1);
      ps += __shfl_xor(ps, 2);
      ps += __shfl_xor(ps, 4);
      ps += __shfl_xor(ps, 8);
      l[r] = l[r] * sc + ps;
      acc[0][r] *= sc; acc[1][r] *= sc; acc[2][r] *= sc; acc[3][r] *= sc;
      const int prow = w * 16 + lg * 4 + r;
      Ps[prow][0 + lr]  = (bf16_t)p0;
      Ps[prow][16 + lr] = (bf16_t)p1;
      Ps[prow][32 + lr] = (bf16_t)p2;
      Ps[prow][48 + lr] = (bf16_t)p3;
    }
    // PV: A = P rows (wave-private LDS slice), B = Vt rows (col = d)
    const bf16x8 ap0 = *(const bf16x8*)&Ps[w * 16 + lr][lg * 8];
    const bf16x8 ap1 = *(const bf16x8*)&Ps[w * 16 + lr][32 + lg * 8];
    __builtin_amdgcn_s_setprio(1);
#pragma unroll
    for (int fn = 0; fn < 4; ++fn) {
      const bf16x8 bv0 = *(const bf16x8*)&Vt[fn * 16 + lr][lg * 8];
      const bf16x8 bv1 = *(const bf16x8*)&Vt[fn * 16 + lr][32 + lg * 8];
      acc[fn] = __builtin_amdgcn_mfma_f32_16x16x32_bf16(ap0, bv0, acc[fn], 0, 0, 0);
      acc[fn] = __builtin_amdgcn_mfma_f32_16x16x32_bf16(ap1, bv1, acc[fn], 0, 0, 0);
    }
    __builtin_amdgcn_s_setprio(0);
  }
  // epilogue: gate & normalize, write bf16 y (B,T,D)
#pragma unroll
  for (int r = 0; r < 4; ++r) {
    const float inv = attn_gate[(size_t)(b * T_ + qpos_r[r]) * H_ + h] / l[r];
#pragma unroll
    for (int fn = 0; fn < 4; ++fn)
      y_buf[(size_t)(b * T_ + qpos_r[r]) * D_ + h * HD_ + fn * 16 + lr] =
          (bf16_t)(acc[fn][r] * inv);
  }
}

extern "C" void kernel_launch(void* const* d_in, const int* in_sizes, int n_in,
                              void* d_out, int out_size, void* d_ws, size_t ws_size,
                              hipStream_t stream) {
  const float* x    = (const float*)d_in[0];
  const float* ve   = (const float*)d_in[1];
  const float* lam  = (const float*)d_in[2];
  const float* cosb = (const float*)d_in[3];
  const float* sinb = (const float*)d_in[4];
  const float* qkvo = (const float*)d_in[5];
  const float* agw  = (const float*)d_in[6];
  const float* vgw  = (const float*)d_in[7];
  const float* ascl = (const float*)d_in[8];
  const int*   docs = (const int*)d_in[9];
  float* out = (float*)d_out;

  const size_t BT = (size_t)B_ * T_;  // 4096
  float* cur = (float*)d_ws;
  bf16_t* x_bf = (bf16_t*)cur;        cur += BT * D_ / 2;
  bf16_t* wq_bf = (bf16_t*)cur;       cur += (size_t)QN_ * D_ / 2;   // [3200][1024]
  bf16_t* wo_bf = (bf16_t*)cur;       cur += (size_t)D_ * D_ / 2;
  bf16_t* qkv_b = (bf16_t*)cur;       cur += BT * QN_ / 2;
  bf16_t* q_bf = (bf16_t*)cur;        cur += BT * D_ / 2;
  bf16_t* k_bf = (bf16_t*)cur;        cur += BT * D_ / 2;
  bf16_t* v_bf = (bf16_t*)cur;        cur += BT * D_ / 2;
  bf16_t* y_bf = (bf16_t*)cur;        cur += BT * D_ / 2;
  float* attn_gate = cur;             cur += BT * H_;

  // casts: x; full qkvo (split wq/wo); gate rows appended to wq
  const int nx4 = (int)(BT * D_ / 4);
  cast_bf16<<<(nx4 + 255) / 256, 256, 0, stream>>>(x, x_bf, nx4);
  const int nq4 = (int)((size_t)4 * D_ * D_ / 4);
  const int ns4 = (int)((size_t)3 * D_ * D_ / 4);
  cast_qkvo<<<(nq4 + 255) / 256, 256, 0, stream>>>(qkvo, wq_bf, wo_bf, nq4, ns4);
  const int ng4 = (int)((size_t)H_ * D_ / 4);
  cast_bf16<<<(2 * ng4 + 255) / 256, 256, 0, stream>>>(agw, wq_bf + (size_t)3072 * D_, ng4);
  cast_bf16<<<(ng4 + 255) / 256, 256, 0, stream>>>(vgw, wq_bf + (size_t)3088 * D_, ng4);

  // 1) QKV + gate-score projection (bf16 MFMA, bf16 out, gates unscaled)
  gemm_bf16<<<dim3(QN_ / 128, BT / 128), 256, 0, stream>>>(
      x_bf, wq_bf, qkv_b, (int)BT, QN_, D_, lam, 0, 3072, 1);

  // 2) rmsnorm + rotary + v-augment + gate sigmoids -> bf16 q/k/v (B,H,T,HD)
  post_kernel<<<(B_ * T_ * H_) / 4, 256, 0, stream>>>(
      qkv_b, ve, cosb, sinb, q_bf, k_bf, v_bf, attn_gate);

  // 3) MFMA flash attention (doc-block-diagonal skip; key-offset fused)
  attn_mfma<<<dim3(T_ / 64, B_ * H_), 256, 0, stream>>>(
      q_bf, k_bf, v_bf, attn_gate, docs, ascl, y_bf);

  // 4) output projection (bf16 MFMA, f32 out)
  gemm_bf16<<<dim3(D_ / 128, BT / 128), 256, 0, stream>>>(
      y_bf, wo_bf, out, (int)BT, D_, D_, lam, 1, D_, 0);
}

// Round 8
// 145.524 us; speedup vs baseline: 1.1066x; 1.1066x over previous
//
#include <hip/hip_runtime.h>
#include <math.h>

#define B_ 2
#define T_ 2048
#define D_ 1024
#define H_ 16
#define HD_ 64
#define EPS_ 1.1920929e-07f
#define VE_SCALE_ 2.0f
#define QN_ 3200   // 3072 qkv cols + 16 attn-gate + 16 ve-gate + 96 pad

#define NX4_ (B_ * T_ * D_ / 4)          // 1048576
#define NS4_ (3 * D_ * D_ / 4)           // 786432
#define NQ4_ (4 * D_ * D_ / 4)           // 1048576
#define NG4_ (H_ * D_ / 4)               // 4096

typedef __bf16 bf16_t;
typedef __bf16 bf16x4 __attribute__((ext_vector_type(4)));
typedef __bf16 bf16x8 __attribute__((ext_vector_type(8)));
typedef float f32x4 __attribute__((ext_vector_type(4)));

__device__ const f32x4 F4ZERO = {0.f, 0.f, 0.f, 0.f};

typedef __attribute__((address_space(1))) const void gvoid_t;
typedef __attribute__((address_space(3))) void lvoid_t;

__device__ __forceinline__ void gl_lds16(const bf16_t* g, bf16_t* l) {
  // async global->LDS, 16B/lane; LDS dest = wave-uniform base + lane*16
  __builtin_amdgcn_global_load_lds((gvoid_t*)g, (lvoid_t*)l, 16, 0, 0);
}

// ------------- single fused f32->bf16 cast for all weight/input buffers ----
// regions: x (NX4), qkvo rows [0,3072)->wq, rows [3072,4096)->wo, agw, vgw
__global__ __launch_bounds__(256) void cast_all(
    const float* __restrict__ x, const float* __restrict__ qkvo,
    const float* __restrict__ agw, const float* __restrict__ vgw,
    bf16_t* __restrict__ x_bf, bf16_t* __restrict__ wq,
    bf16_t* __restrict__ wo)
{
  const int i = blockIdx.x * 256 + threadIdx.x;
  const float4* src;
  bf16x4* dst;
  if (i < NX4_) {
    src = (const float4*)x + i;
    dst = (bf16x4*)x_bf + i;
  } else if (i < NX4_ + NS4_) {
    const int j = i - NX4_;
    src = (const float4*)qkvo + j;
    dst = (bf16x4*)wq + j;
  } else if (i < NX4_ + NQ4_) {
    const int j = i - NX4_;
    src = (const float4*)qkvo + j;
    dst = (bf16x4*)wo + (j - NS4_);
  } else if (i < NX4_ + NQ4_ + NG4_) {
    const int j = i - NX4_ - NQ4_;
    src = (const float4*)agw + j;
    dst = (bf16x4*)(wq + (size_t)3072 * D_) + j;
  } else {
    const int j = i - NX4_ - NQ4_ - NG4_;
    src = (const float4*)vgw + j;
    dst = (bf16x4*)(wq + (size_t)3088 * D_) + j;
  }
  const float4 v = *src;
  bf16x4 o = {(bf16_t)v.x, (bf16_t)v.y, (bf16_t)v.z, (bf16_t)v.w};
  *dst = o;
}

// ---------------- bf16 MFMA GEMM (m97/r4 structure + XCD swizzle) ----------
// C = scale * A @ W^T. 128x128 tile, BK=32, 4 waves (2x2 of 64x64),
// global_load_lds width-16 into linear LDS [128][32], 2-barrier K-loop,
// 16 MFMA/wave/K-step. Bijective XCD swizzle (grids %8==0) keeps each
// XCD's L2 on a contiguous block range (r6/r7 A/B: FETCH 34.7 vs 63.3 MB).
// Cols >= n_scaled skip the lambda scale (gate columns). out_bf: bf16 C.
__global__ __launch_bounds__(256) void gemm_bf16(
    const bf16_t* __restrict__ A, const bf16_t* __restrict__ W,
    void* __restrict__ Cout, int M, int N, int K,
    const float* __restrict__ lam, int li, int n_scaled, int out_bf)
{
  const float scale = lam[li];
  __shared__ bf16_t As[128][32];
  __shared__ bf16_t Bs[128][32];
  const int tid = threadIdx.x;
  const int lane = tid & 63, w = tid >> 6;
  const int lr = lane & 15, lg = lane >> 4;
  const int wr = w >> 1, wc = w & 1;

  const int nwg = gridDim.x * gridDim.y;
  int bid = blockIdx.y * gridDim.x + blockIdx.x;
  bid = (bid & 7) * (nwg >> 3) + (bid >> 3);
  const int row0 = (bid / gridDim.x) * 128;
  const int col0 = (bid % gridDim.x) * 128;

  // staging: wave w covers tile rows [w*32, +32); each gl_lds covers 16 rows
  const int srow = w * 32 + (lane >> 2);
  const int scol = (lane & 3) * 8;
  const bf16_t* Ag = A + (size_t)(row0 + srow) * K + scol;
  const bf16_t* Wg = W + (size_t)(col0 + srow) * K + scol;
  bf16_t* AsB0 = &As[w * 32][0];
  bf16_t* AsB1 = &As[w * 32 + 16][0];
  bf16_t* BsB0 = &Bs[w * 32][0];
  bf16_t* BsB1 = &Bs[w * 32 + 16][0];
  const size_t r16 = (size_t)16 * K;

  f32x4 acc[4][4];
#pragma unroll
  for (int i = 0; i < 4; ++i)
#pragma unroll
    for (int j = 0; j < 4; ++j) acc[i][j] = F4ZERO;

  for (int k0 = 0; k0 < K; k0 += 32) {
    __syncthreads();  // previous K-tile fully consumed
    gl_lds16(Ag + k0, AsB0);
    gl_lds16(Ag + r16 + k0, AsB1);
    gl_lds16(Wg + k0, BsB0);
    gl_lds16(Wg + r16 + k0, BsB1);
    __syncthreads();  // drains vmcnt(0): staged data visible

    bf16x8 af[4], bfr[4];
#pragma unroll
    for (int fm = 0; fm < 4; ++fm)
      af[fm] = *(const bf16x8*)&As[wr * 64 + fm * 16 + lr][lg * 8];
#pragma unroll
    for (int fn = 0; fn < 4; ++fn)
      bfr[fn] = *(const bf16x8*)&Bs[wc * 64 + fn * 16 + lr][lg * 8];
#pragma unroll
    for (int fm = 0; fm < 4; ++fm)
#pragma unroll
      for (int fn = 0; fn < 4; ++fn)
        acc[fm][fn] = __builtin_amdgcn_mfma_f32_16x16x32_bf16(
            af[fm], bfr[fn], acc[fm][fn], 0, 0, 0);
  }
  // epilogue: C/D layout col=lane&15, row=(lane>>4)*4+reg  [m89]
#pragma unroll
  for (int fm = 0; fm < 4; ++fm)
#pragma unroll
    for (int fn = 0; fn < 4; ++fn)
#pragma unroll
      for (int r = 0; r < 4; ++r) {
        const int row = row0 + wr * 64 + fm * 16 + lg * 4 + r;
        const int col = col0 + wc * 64 + fn * 16 + lr;
        const float v = acc[fm][fn][r] * ((col < n_scaled) ? scale : 1.f);
        if (out_bf) ((bf16_t*)Cout)[(size_t)row * N + col] = (bf16_t)v;
        else        ((float*)Cout)[(size_t)row * N + col] = v;
      }
}

// -------- rmsnorm + rotary + v-augment + gate sigmoids, bf16 out --------
// qkv_b is bf16 (B*T, QN_): cols [0,3072) = qkv, [3072,3088) = attn-gate
// scores, [3088,3104) = ve-gate scores (both unscaled by lambda).
__global__ __launch_bounds__(256) void post_kernel(
    const bf16_t* __restrict__ qkv_b, const float* __restrict__ ve,
    const float* __restrict__ cosb, const float* __restrict__ sinb,
    bf16_t* __restrict__ q_bf, bf16_t* __restrict__ k_bf,
    bf16_t* __restrict__ v_bf, float* __restrict__ attn_gate)
{
  const int wid = (blockIdx.x * blockDim.x + threadIdx.x) >> 6;
  const int lane = threadIdx.x & 63;
  const int h = wid & (H_ - 1);
  const int t = (wid >> 4) & (T_ - 1);
  const int b = wid >> 15;
  const size_t row = (size_t)(b * T_ + t) * QN_;
  const float qraw = (float)qkv_b[row + h * HD_ + lane];
  const float kraw = (float)qkv_b[row + D_ + h * HD_ + lane];
  const float vraw = (float)qkv_b[row + 2 * D_ + h * HD_ + lane];
  const float c = cosb[t * (HD_ / 2) + (lane & 31)];
  const float s = sinb[t * (HD_ / 2) + (lane & 31)];

  float ssq = qraw * qraw;
  float ssk = kraw * kraw;
#pragma unroll
  for (int off = 32; off > 0; off >>= 1) {
    ssq += __shfl_xor(ssq, off);
    ssk += __shfl_xor(ssk, off);
  }
  const float qn = qraw * rsqrtf(ssq * (1.f / 64.f) + EPS_);
  const float kn = kraw * rsqrtf(ssk * (1.f / 64.f) + EPS_);
  const float qpartner = __shfl_xor(qn, 32);
  const float kpartner = __shfl_xor(kn, 32);
  const float qo = (lane < 32) ? fmaf(qn, c, qpartner * s)
                               : fmaf(qn, c, -qpartner * s);
  const float ko = (lane < 32) ? fmaf(kn, c, kpartner * s)
                               : fmaf(kn, c, -kpartner * s);
  const int bh = b * H_ + h;
  const size_t oidx = ((size_t)bh * T_ + t) * HD_ + lane;
  q_bf[oidx] = (bf16_t)qo;
  k_bf[oidx] = (bf16_t)ko;
  // gate scores (broadcast bf16 reads)
  const float gv = VE_SCALE_ / (1.f + __expf(-(float)qkv_b[row + 3088 + h]));
  const float vv = fmaf(gv, ve[(size_t)(b * T_ + t) * D_ + h * HD_ + lane], vraw);
  v_bf[oidx] = (bf16_t)vv;
  if (lane == 0)
    attn_gate[(b * T_ + t) * H_ + h] =
        1.f / (1.f + __expf(-(float)qkv_b[row + 3072 + h]));
}

// ---------------- MFMA flash attention, doc-block-diagonal ----------------
// Grid (32 q-tiles, 32 bh); block = 4 waves, wave w owns q-rows w*16..+16.
// docs sorted => q-tile qt only attends kt in [ktlo, qt].
__global__ __launch_bounds__(256) void attn_mfma(
    const bf16_t* __restrict__ q_buf, const bf16_t* __restrict__ k_tmp,
    const bf16_t* __restrict__ v_buf, const float* __restrict__ attn_gate,
    const int* __restrict__ docs, const float* __restrict__ scale_ptr,
    bf16_t* __restrict__ y_buf)
{
  const int qt = blockIdx.x, bh = blockIdx.y;
  const int b = bh >> 4, h = bh & 15;
  const int tid = threadIdx.x;
  const int w = tid >> 6, lane = tid & 63;
  const int lr = lane & 15, lg = lane >> 4;
  const float scale = scale_ptr[0];
  __shared__ bf16_t Ks[64][72];
  __shared__ bf16_t Vt[64][72];
  __shared__ bf16_t Ps[64][72];
  __shared__ int dk[64];

  // doc-range lower bound for this q-tile (docs sorted)
  const int dlo = docs[qt * 64];
  const unsigned long long bal =
      __ballot((lane <= qt) && (docs[lane * 64 + 63] >= dlo));
  const int ktlo = __ffsll(bal) - 1;

  // Q a-frags hoisted (A-frag: row = lane&15, k = (lane>>4)*8+j)
  const bf16_t* qp = q_buf + ((size_t)bh * T_ + qt * 64 + w * 16 + lr) * HD_;
  const bf16x8 aq0 = *(const bf16x8*)(qp + lg * 8);
  const bf16x8 aq1 = *(const bf16x8*)(qp + 32 + lg * 8);
  int qpos_r[4], docq_r[4];
#pragma unroll
  for (int r = 0; r < 4; ++r) {
    qpos_r[r] = qt * 64 + w * 16 + lg * 4 + r;
    docq_r[r] = docs[qpos_r[r]];
  }
  f32x4 acc[4];
#pragma unroll
  for (int fn = 0; fn < 4; ++fn) acc[fn] = F4ZERO;
  float m[4] = {-1e30f, -1e30f, -1e30f, -1e30f};
  float l[4] = {0.f, 0.f, 0.f, 0.f};

#pragma unroll 1
  for (int kt = ktlo; kt <= qt; ++kt) {
    __syncthreads();
#pragma unroll
    for (int i = 0; i < 2; ++i) {
      const int idx = i * 256 + tid;
      // K staging (fused key-offset: channels [16,32)|[48,64) from t-1)
      const int krow = idx >> 3;
      const int c8 = (idx & 7) << 3;
      const int gk = kt * 64 + krow;
      const int gks = (((c8 & 16) != 0) && gk > 0) ? gk - 1 : gk;
      *(bf16x8*)&Ks[krow][c8] =
          *(const bf16x8*)(k_tmp + ((size_t)bh * T_ + gks) * HD_ + c8);
      // V transpose staging
      const int kpos = idx & 63;
      const int d0 = (idx >> 6) << 3;
      const bf16x8 vv =
          *(const bf16x8*)(v_buf + ((size_t)bh * T_ + kt * 64 + kpos) * HD_ + d0);
#pragma unroll
      for (int j = 0; j < 8; ++j) Vt[d0 + j][kpos] = vv[j];
    }
    if (tid < 64) dk[tid] = docs[kt * 64 + tid];
    __syncthreads();

    // S = Q K^T  (B-frag: col = lane&15 = kpos, k = d contiguous)
    f32x4 s[4];
#pragma unroll
    for (int fn = 0; fn < 4; ++fn) {
      const bf16x8 bk0 = *(const bf16x8*)&Ks[fn * 16 + lr][lg * 8];
      const bf16x8 bk1 = *(const bf16x8*)&Ks[fn * 16 + lr][32 + lg * 8];
      f32x4 z = F4ZERO;
      z = __builtin_amdgcn_mfma_f32_16x16x32_bf16(aq0, bk0, z, 0, 0, 0);
      s[fn] = __builtin_amdgcn_mfma_f32_16x16x32_bf16(aq1, bk1, z, 0, 0, 0);
    }
    // mask + scale (lane holds rows lg*4+r, col fn*16+lr of the 64x64 S)
    const bool strict = (kt < qt);
#pragma unroll
    for (int fn = 0; fn < 4; ++fn) {
      const int kd = dk[fn * 16 + lr];
      const int kp = kt * 64 + fn * 16 + lr;
#pragma unroll
      for (int r = 0; r < 4; ++r) {
        const bool valid = (kd == docq_r[r]) && (strict || kp <= qpos_r[r]);
        s[fn][r] = valid ? s[fn][r] * scale : -3.0e38f;
      }
    }
    // online softmax (row reduce across 16-lane col group) + P write
#pragma unroll
    for (int r = 0; r < 4; ++r) {
      float cm = fmaxf(fmaxf(s[0][r], s[1][r]), fmaxf(s[2][r], s[3][r]));
      cm = fmaxf(cm, __shfl_xor(cm, 1));
      cm = fmaxf(cm, __shfl_xor(cm, 2));
      cm = fmaxf(cm, __shfl_xor(cm, 4));
      cm = fmaxf(cm, __shfl_xor(cm, 8));
      const float mn = fmaxf(m[r], cm);
      const float sc = __expf(m[r] - mn);
      m[r] = mn;
      const float p0 = __expf(s[0][r] - mn);
      const float p1 = __expf(s[1][r] - mn);
      const float p2 = __expf(s[2][r] - mn);
      const float p3 = __expf(s[3][r] - mn);
      float ps = (p0 + p1) + (p2 + p3);
      ps += __shfl_xor(ps, 1);
      ps += __shfl_xor(ps, 2);
      ps += __shfl_xor(ps, 4);
      ps += __shfl_xor(ps, 8);
      l[r] = l[r] * sc + ps;
      acc[0][r] *= sc; acc[1][r] *= sc; acc[2][r] *= sc; acc[3][r] *= sc;
      const int prow = w * 16 + lg * 4 + r;
      Ps[prow][0 + lr]  = (bf16_t)p0;
      Ps[prow][16 + lr] = (bf16_t)p1;
      Ps[prow][32 + lr] = (bf16_t)p2;
      Ps[prow][48 + lr] = (bf16_t)p3;
    }
    // PV: A = P rows (wave-private LDS slice), B = Vt rows (col = d)
    const bf16x8 ap0 = *(const bf16x8*)&Ps[w * 16 + lr][lg * 8];
    const bf16x8 ap1 = *(const bf16x8*)&Ps[w * 16 + lr][32 + lg * 8];
#pragma unroll
    for (int fn = 0; fn < 4; ++fn) {
      const bf16x8 bv0 = *(const bf16x8*)&Vt[fn * 16 + lr][lg * 8];
      const bf16x8 bv1 = *(const bf16x8*)&Vt[fn * 16 + lr][32 + lg * 8];
      acc[fn] = __builtin_amdgcn_mfma_f32_16x16x32_bf16(ap0, bv0, acc[fn], 0, 0, 0);
      acc[fn] = __builtin_amdgcn_mfma_f32_16x16x32_bf16(ap1, bv1, acc[fn], 0, 0, 0);
    }
  }
  // epilogue: gate & normalize, write bf16 y (B,T,D)
#pragma unroll
  for (int r = 0; r < 4; ++r) {
    const float inv = attn_gate[(size_t)(b * T_ + qpos_r[r]) * H_ + h] / l[r];
#pragma unroll
    for (int fn = 0; fn < 4; ++fn)
      y_buf[(size_t)(b * T_ + qpos_r[r]) * D_ + h * HD_ + fn * 16 + lr] =
          (bf16_t)(acc[fn][r] * inv);
  }
}

extern "C" void kernel_launch(void* const* d_in, const int* in_sizes, int n_in,
                              void* d_out, int out_size, void* d_ws, size_t ws_size,
                              hipStream_t stream) {
  const float* x    = (const float*)d_in[0];
  const float* ve   = (const float*)d_in[1];
  const float* lam  = (const float*)d_in[2];
  const float* cosb = (const float*)d_in[3];
  const float* sinb = (const float*)d_in[4];
  const float* qkvo = (const float*)d_in[5];
  const float* agw  = (const float*)d_in[6];
  const float* vgw  = (const float*)d_in[7];
  const float* ascl = (const float*)d_in[8];
  const int*   docs = (const int*)d_in[9];
  float* out = (float*)d_out;

  const size_t BT = (size_t)B_ * T_;  // 4096
  float* cur = (float*)d_ws;
  bf16_t* x_bf = (bf16_t*)cur;        cur += BT * D_ / 2;
  bf16_t* wq_bf = (bf16_t*)cur;       cur += (size_t)QN_ * D_ / 2;   // [3200][1024]
  bf16_t* wo_bf = (bf16_t*)cur;       cur += (size_t)D_ * D_ / 2;
  bf16_t* qkv_b = (bf16_t*)cur;       cur += BT * QN_ / 2;
  bf16_t* q_bf = (bf16_t*)cur;        cur += BT * D_ / 2;
  bf16_t* k_bf = (bf16_t*)cur;        cur += BT * D_ / 2;
  bf16_t* v_bf = (bf16_t*)cur;        cur += BT * D_ / 2;
  bf16_t* y_bf = (bf16_t*)cur;        cur += BT * D_ / 2;
  float* attn_gate = cur;             cur += BT * H_;

  // 0) single fused cast: x, wq (qkv rows + gate rows), wo
  cast_all<<<(NX4_ + NQ4_ + 2 * NG4_) / 256, 256, 0, stream>>>(
      x, qkvo, agw, vgw, x_bf, wq_bf, wo_bf);

  // 1) QKV + gate-score projection (bf16 MFMA, bf16 out, gates unscaled)
  gemm_bf16<<<dim3(QN_ / 128, BT / 128), 256, 0, stream>>>(
      x_bf, wq_bf, qkv_b, (int)BT, QN_, D_, lam, 0, 3072, 1);

  // 2) rmsnorm + rotary + v-augment + gate sigmoids -> bf16 q/k/v (B,H,T,HD)
  post_kernel<<<(B_ * T_ * H_) / 4, 256, 0, stream>>>(
      qkv_b, ve, cosb, sinb, q_bf, k_bf, v_bf, attn_gate);

  // 3) MFMA flash attention (doc-block-diagonal skip; key-offset fused)
  attn_mfma<<<dim3(T_ / 64, B_ * H_), 256, 0, stream>>>(
      q_bf, k_bf, v_bf, attn_gate, docs, ascl, y_bf);

  // 4) output projection (bf16 MFMA, f32 out)
  gemm_bf16<<<dim3(D_ / 128, BT / 128), 256, 0, stream>>>(
      y_bf, wo_bf, out, (int)BT, D_, D_, lam, 1, D_, 0);
}

// Round 9
// 134.730 us; speedup vs baseline: 1.1953x; 1.0801x over previous
//
#include <hip/hip_runtime.h>
#include <math.h>

#define B_ 2
#define T_ 2048
#define D_ 1024
#define H_ 16
#define HD_ 64
#define EPS_ 1.1920929e-07f
#define VE_SCALE_ 2.0f

#define NX4_ (B_ * T_ * D_ / 4)          // 1048576
#define NS4_ (3 * D_ * D_ / 4)           // 786432
#define NQ4_ (4 * D_ * D_ / 4)           // 1048576
#define NG4_ (H_ * D_ / 4)               // 4096

typedef __bf16 bf16_t;
typedef __bf16 bf16x4 __attribute__((ext_vector_type(4)));
typedef __bf16 bf16x8 __attribute__((ext_vector_type(8)));
typedef float f32x4 __attribute__((ext_vector_type(4)));

__device__ const f32x4 F4ZERO = {0.f, 0.f, 0.f, 0.f};

typedef __attribute__((address_space(1))) const void gvoid_t;
typedef __attribute__((address_space(3))) void lvoid_t;

__device__ __forceinline__ void gl_lds16(const bf16_t* g, bf16_t* l) {
  // async global->LDS, 16B/lane; LDS dest = wave-uniform base + lane*16
  __builtin_amdgcn_global_load_lds((gvoid_t*)g, (lvoid_t*)l, 16, 0, 0);
}

// ------------- single fused f32->bf16 cast ---------------------------------
// regions: x->x_bf, qkvo rows [0,3072)->wq, [3072,4096)->wo, agw/vgw->wg
__global__ __launch_bounds__(256) void cast_all(
    const float* __restrict__ x, const float* __restrict__ qkvo,
    const float* __restrict__ agw, const float* __restrict__ vgw,
    bf16_t* __restrict__ x_bf, bf16_t* __restrict__ wq,
    bf16_t* __restrict__ wo, bf16_t* __restrict__ wg)
{
  const int i = blockIdx.x * 256 + threadIdx.x;
  const float4* src;
  bf16x4* dst;
  if (i < NX4_) {
    src = (const float4*)x + i;
    dst = (bf16x4*)x_bf + i;
  } else if (i < NX4_ + NS4_) {
    const int j = i - NX4_;
    src = (const float4*)qkvo + j;
    dst = (bf16x4*)wq + j;
  } else if (i < NX4_ + NQ4_) {
    const int j = i - NX4_;
    src = (const float4*)qkvo + j;
    dst = (bf16x4*)wo + (j - NS4_);
  } else if (i < NX4_ + NQ4_ + NG4_) {
    const int j = i - NX4_ - NQ4_;
    src = (const float4*)agw + j;
    dst = (bf16x4*)wg + j;
  } else {
    const int j = i - NX4_ - NQ4_ - NG4_;
    src = (const float4*)vgw + j;
    dst = (bf16x4*)wg + NG4_ + j;
  }
  const float4 v = *src;
  bf16x4 o = {(bf16_t)v.x, (bf16_t)v.y, (bf16_t)v.z, (bf16_t)v.w};
  *dst = o;
}

// ---------------- bf16 MFMA GEMM (m97/r4 structure + XCD swizzle) ----------
// C = scale * A @ W^T. 128x128 tile, BK=32, 4 waves (2x2 of 64x64),
// global_load_lds width-16 into linear LDS [128][32], 2-barrier K-loop.
// GRID MUST BE k*256 BLOCKS (tail-free): 768 for QKV, 256 for out-proj
// (r4 vs r6-r8 A/B: a 32-block tail cost ~25 us).
__global__ __launch_bounds__(256) void gemm_bf16(
    const bf16_t* __restrict__ A, const bf16_t* __restrict__ W,
    void* __restrict__ Cout, int M, int N, int K,
    const float* __restrict__ lam, int li, int out_bf)
{
  const float scale = lam[li];
  __shared__ bf16_t As[128][32];
  __shared__ bf16_t Bs[128][32];
  const int tid = threadIdx.x;
  const int lane = tid & 63, w = tid >> 6;
  const int lr = lane & 15, lg = lane >> 4;
  const int wr = w >> 1, wc = w & 1;

  const int nwg = gridDim.x * gridDim.y;
  int bid = blockIdx.y * gridDim.x + blockIdx.x;
  bid = (bid & 7) * (nwg >> 3) + (bid >> 3);
  const int row0 = (bid / gridDim.x) * 128;
  const int col0 = (bid % gridDim.x) * 128;

  // staging: wave w covers tile rows [w*32, +32); each gl_lds covers 16 rows
  const int srow = w * 32 + (lane >> 2);
  const int scol = (lane & 3) * 8;
  const bf16_t* Ag = A + (size_t)(row0 + srow) * K + scol;
  const bf16_t* Wg = W + (size_t)(col0 + srow) * K + scol;
  bf16_t* AsB0 = &As[w * 32][0];
  bf16_t* AsB1 = &As[w * 32 + 16][0];
  bf16_t* BsB0 = &Bs[w * 32][0];
  bf16_t* BsB1 = &Bs[w * 32 + 16][0];
  const size_t r16 = (size_t)16 * K;

  f32x4 acc[4][4];
#pragma unroll
  for (int i = 0; i < 4; ++i)
#pragma unroll
    for (int j = 0; j < 4; ++j) acc[i][j] = F4ZERO;

  for (int k0 = 0; k0 < K; k0 += 32) {
    __syncthreads();  // previous K-tile fully consumed
    gl_lds16(Ag + k0, AsB0);
    gl_lds16(Ag + r16 + k0, AsB1);
    gl_lds16(Wg + k0, BsB0);
    gl_lds16(Wg + r16 + k0, BsB1);
    __syncthreads();  // drains vmcnt(0): staged data visible

    bf16x8 af[4], bfr[4];
#pragma unroll
    for (int fm = 0; fm < 4; ++fm)
      af[fm] = *(const bf16x8*)&As[wr * 64 + fm * 16 + lr][lg * 8];
#pragma unroll
    for (int fn = 0; fn < 4; ++fn)
      bfr[fn] = *(const bf16x8*)&Bs[wc * 64 + fn * 16 + lr][lg * 8];
#pragma unroll
    for (int fm = 0; fm < 4; ++fm)
#pragma unroll
      for (int fn = 0; fn < 4; ++fn)
        acc[fm][fn] = __builtin_amdgcn_mfma_f32_16x16x32_bf16(
            af[fm], bfr[fn], acc[fm][fn], 0, 0, 0);
  }
  // epilogue: C/D layout col=lane&15, row=(lane>>4)*4+reg  [m89]
#pragma unroll
  for (int fm = 0; fm < 4; ++fm)
#pragma unroll
    for (int fn = 0; fn < 4; ++fn)
#pragma unroll
      for (int r = 0; r < 4; ++r) {
        const int row = row0 + wr * 64 + fm * 16 + lg * 4 + r;
        const int col = col0 + wc * 64 + fn * 16 + lr;
        const float v = acc[fm][fn][r] * scale;
        if (out_bf) ((bf16_t*)Cout)[(size_t)row * N + col] = (bf16_t)v;
        else        ((float*)Cout)[(size_t)row * N + col] = v;
      }
}

// -------- post: gates (from LDS-staged x) + rmsnorm + rotary + v-augment ---
// One block per (b,t). x row staged once in LDS; 32 gate dot-products
// (weights bf16, 64KB resident in L2 across blocks); then each wave handles
// 4 heads: rmsnorm+rotary q/k, v += ve_gate*ve. Outputs bf16 (B,H,T,HD).
__global__ __launch_bounds__(256) void post_kernel(
    const float* __restrict__ x, const bf16_t* __restrict__ qkv_b,
    const float* __restrict__ ve, const float* __restrict__ cosb,
    const float* __restrict__ sinb, const bf16_t* __restrict__ wg,
    bf16_t* __restrict__ q_bf, bf16_t* __restrict__ k_bf,
    bf16_t* __restrict__ v_bf, float* __restrict__ attn_gate)
{
  const int bt = blockIdx.x;           // 0..B*T-1
  const int b = bt >> 11, t = bt & (T_ - 1);
  const int tid = threadIdx.x;
  __shared__ float xs[D_];
  __shared__ float gsc[32];

  *(float4*)&xs[tid * 4] = ((const float4*)(x + (size_t)bt * D_))[tid];
  __syncthreads();

  // gate dots: output g = tid>>3 (0..31: 0-15 attn, 16-31 ve), segment c=tid&7
  {
    const int g = tid >> 3, cg = tid & 7;
    const bf16x8* wrow = (const bf16x8*)(wg + (size_t)g * D_);
    float sum = 0.f;
#pragma unroll
    for (int j = 0; j < 16; ++j) {
      const bf16x8 w8 = wrow[cg + 8 * j];
      const float* xp = &xs[(cg + 8 * j) * 8];
#pragma unroll
      for (int e = 0; e < 8; ++e) sum = fmaf((float)w8[e], xp[e], sum);
    }
    sum += __shfl_xor(sum, 1);
    sum += __shfl_xor(sum, 2);
    sum += __shfl_xor(sum, 4);
    if (cg == 0)
      gsc[g] = (g < 16 ? 1.f : VE_SCALE_) / (1.f + __expf(-sum));
  }
  __syncthreads();

  // per-head work: wave w handles heads w, w+4, w+8, w+12
  const int w = tid >> 6, lane = tid & 63;
  const float c = cosb[t * 32 + (lane & 31)];
  const float s = sinb[t * 32 + (lane & 31)];
  const size_t row = (size_t)bt * 3072;
#pragma unroll
  for (int i = 0; i < 4; ++i) {
    const int h = w + i * 4;
    const float qraw = (float)qkv_b[row + h * HD_ + lane];
    const float kraw = (float)qkv_b[row + D_ + h * HD_ + lane];
    const float vraw = (float)qkv_b[row + 2 * D_ + h * HD_ + lane];
    float ssq = qraw * qraw, ssk = kraw * kraw;
#pragma unroll
    for (int off = 32; off > 0; off >>= 1) {
      ssq += __shfl_xor(ssq, off);
      ssk += __shfl_xor(ssk, off);
    }
    const float qn = qraw * rsqrtf(ssq * (1.f / 64.f) + EPS_);
    const float kn = kraw * rsqrtf(ssk * (1.f / 64.f) + EPS_);
    const float qpartner = __shfl_xor(qn, 32);
    const float kpartner = __shfl_xor(kn, 32);
    const float qo = (lane < 32) ? fmaf(qn, c, qpartner * s)
                                 : fmaf(qn, c, -qpartner * s);
    const float ko = (lane < 32) ? fmaf(kn, c, kpartner * s)
                                 : fmaf(kn, c, -kpartner * s);
    const size_t oidx = ((size_t)(b * H_ + h) * T_ + t) * HD_ + lane;
    q_bf[oidx] = (bf16_t)qo;
    k_bf[oidx] = (bf16_t)ko;
    const float vv = fmaf(gsc[16 + h], ve[(size_t)bt * D_ + h * HD_ + lane], vraw);
    v_bf[oidx] = (bf16_t)vv;
    if (lane == 0) attn_gate[bt * H_ + h] = gsc[h];
  }
}

// ---------------- MFMA flash attention, doc-block-diagonal ----------------
// Grid (32 q-tiles, 32 bh); block = 4 waves, wave w owns q-rows w*16..+16.
// docs sorted => q-tile qt only attends kt in [ktlo, qt].
__global__ __launch_bounds__(256) void attn_mfma(
    const bf16_t* __restrict__ q_buf, const bf16_t* __restrict__ k_tmp,
    const bf16_t* __restrict__ v_buf, const float* __restrict__ attn_gate,
    const int* __restrict__ docs, const float* __restrict__ scale_ptr,
    bf16_t* __restrict__ y_buf)
{
  const int qt = blockIdx.x, bh = blockIdx.y;
  const int b = bh >> 4, h = bh & 15;
  const int tid = threadIdx.x;
  const int w = tid >> 6, lane = tid & 63;
  const int lr = lane & 15, lg = lane >> 4;
  const float scale = scale_ptr[0];
  __shared__ bf16_t Ks[64][72];
  __shared__ bf16_t Vt[64][72];
  __shared__ bf16_t Ps[64][72];
  __shared__ int dk[64];

  // doc-range lower bound for this q-tile (docs sorted)
  const int dlo = docs[qt * 64];
  const unsigned long long bal =
      __ballot((lane <= qt) && (docs[lane * 64 + 63] >= dlo));
  const int ktlo = __ffsll(bal) - 1;

  // Q a-frags hoisted (A-frag: row = lane&15, k = (lane>>4)*8+j)
  const bf16_t* qp = q_buf + ((size_t)bh * T_ + qt * 64 + w * 16 + lr) * HD_;
  const bf16x8 aq0 = *(const bf16x8*)(qp + lg * 8);
  const bf16x8 aq1 = *(const bf16x8*)(qp + 32 + lg * 8);
  int qpos_r[4], docq_r[4];
#pragma unroll
  for (int r = 0; r < 4; ++r) {
    qpos_r[r] = qt * 64 + w * 16 + lg * 4 + r;
    docq_r[r] = docs[qpos_r[r]];
  }
  f32x4 acc[4];
#pragma unroll
  for (int fn = 0; fn < 4; ++fn) acc[fn] = F4ZERO;
  float m[4] = {-1e30f, -1e30f, -1e30f, -1e30f};
  float l[4] = {0.f, 0.f, 0.f, 0.f};

#pragma unroll 1
  for (int kt = ktlo; kt <= qt; ++kt) {
    __syncthreads();
#pragma unroll
    for (int i = 0; i < 2; ++i) {
      const int idx = i * 256 + tid;
      // K staging (fused key-offset: channels [16,32)|[48,64) from t-1)
      const int krow = idx >> 3;
      const int c8 = (idx & 7) << 3;
      const int gk = kt * 64 + krow;
      const int gks = (((c8 & 16) != 0) && gk > 0) ? gk - 1 : gk;
      *(bf16x8*)&Ks[krow][c8] =
          *(const bf16x8*)(k_tmp + ((size_t)bh * T_ + gks) * HD_ + c8);
      // V transpose staging
      const int kpos = idx & 63;
      const int d0 = (idx >> 6) << 3;
      const bf16x8 vv =
          *(const bf16x8*)(v_buf + ((size_t)bh * T_ + kt * 64 + kpos) * HD_ + d0);
#pragma unroll
      for (int j = 0; j < 8; ++j) Vt[d0 + j][kpos] = vv[j];
    }
    if (tid < 64) dk[tid] = docs[kt * 64 + tid];
    __syncthreads();

    // S = Q K^T  (B-frag: col = lane&15 = kpos, k = d contiguous)
    f32x4 s[4];
#pragma unroll
    for (int fn = 0; fn < 4; ++fn) {
      const bf16x8 bk0 = *(const bf16x8*)&Ks[fn * 16 + lr][lg * 8];
      const bf16x8 bk1 = *(const bf16x8*)&Ks[fn * 16 + lr][32 + lg * 8];
      f32x4 z = F4ZERO;
      z = __builtin_amdgcn_mfma_f32_16x16x32_bf16(aq0, bk0, z, 0, 0, 0);
      s[fn] = __builtin_amdgcn_mfma_f32_16x16x32_bf16(aq1, bk1, z, 0, 0, 0);
    }
    // mask + scale (lane holds rows lg*4+r, col fn*16+lr of the 64x64 S)
    const bool strict = (kt < qt);
#pragma unroll
    for (int fn = 0; fn < 4; ++fn) {
      const int kd = dk[fn * 16 + lr];
      const int kp = kt * 64 + fn * 16 + lr;
#pragma unroll
      for (int r = 0; r < 4; ++r) {
        const bool valid = (kd == docq_r[r]) && (strict || kp <= qpos_r[r]);
        s[fn][r] = valid ? s[fn][r] * scale : -3.0e38f;
      }
    }
    // online softmax (row reduce across 16-lane col group) + P write
#pragma unroll
    for (int r = 0; r < 4; ++r) {
      float cm = fmaxf(fmaxf(s[0][r], s[1][r]), fmaxf(s[2][r], s[3][r]));
      cm = fmaxf(cm, __shfl_xor(cm, 1));
      cm = fmaxf(cm, __shfl_xor(cm, 2));
      cm = fmaxf(cm, __shfl_xor(cm, 4));
      cm = fmaxf(cm, __shfl_xor(cm, 8));
      const float mn = fmaxf(m[r], cm);
      const float sc = __expf(m[r] - mn);
      m[r] = mn;
      const float p0 = __expf(s[0][r] - mn);
      const float p1 = __expf(s[1][r] - mn);
      const float p2 = __expf(s[2][r] - mn);
      const float p3 = __expf(s[3][r] - mn);
      float ps = (p0 + p1) + (p2 + p3);
      ps += __shfl_xor(ps, 1);
      ps += __shfl_xor(ps, 2);
      ps += __shfl_xor(ps, 4);
      ps += __shfl_xor(ps, 8);
      l[r] = l[r] * sc + ps;
      acc[0][r] *= sc; acc[1][r] *= sc; acc[2][r] *= sc; acc[3][r] *= sc;
      const int prow = w * 16 + lg * 4 + r;
      Ps[prow][0 + lr]  = (bf16_t)p0;
      Ps[prow][16 + lr] = (bf16_t)p1;
      Ps[prow][32 + lr] = (bf16_t)p2;
      Ps[prow][48 + lr] = (bf16_t)p3;
    }
    // PV: A = P rows (wave-private LDS slice), B = Vt rows (col = d)
    const bf16x8 ap0 = *(const bf16x8*)&Ps[w * 16 + lr][lg * 8];
    const bf16x8 ap1 = *(const bf16x8*)&Ps[w * 16 + lr][32 + lg * 8];
#pragma unroll
    for (int fn = 0; fn < 4; ++fn) {
      const bf16x8 bv0 = *(const bf16x8*)&Vt[fn * 16 + lr][lg * 8];
      const bf16x8 bv1 = *(const bf16x8*)&Vt[fn * 16 + lr][32 + lg * 8];
      acc[fn] = __builtin_amdgcn_mfma_f32_16x16x32_bf16(ap0, bv0, acc[fn], 0, 0, 0);
      acc[fn] = __builtin_amdgcn_mfma_f32_16x16x32_bf16(ap1, bv1, acc[fn], 0, 0, 0);
    }
  }
  // epilogue: gate & normalize, write bf16 y (B,T,D)
#pragma unroll
  for (int r = 0; r < 4; ++r) {
    const float inv = attn_gate[(size_t)(b * T_ + qpos_r[r]) * H_ + h] / l[r];
#pragma unroll
    for (int fn = 0; fn < 4; ++fn)
      y_buf[(size_t)(b * T_ + qpos_r[r]) * D_ + h * HD_ + fn * 16 + lr] =
          (bf16_t)(acc[fn][r] * inv);
  }
}

extern "C" void kernel_launch(void* const* d_in, const int* in_sizes, int n_in,
                              void* d_out, int out_size, void* d_ws, size_t ws_size,
                              hipStream_t stream) {
  const float* x    = (const float*)d_in[0];
  const float* ve   = (const float*)d_in[1];
  const float* lam  = (const float*)d_in[2];
  const float* cosb = (const float*)d_in[3];
  const float* sinb = (const float*)d_in[4];
  const float* qkvo = (const float*)d_in[5];
  const float* agw  = (const float*)d_in[6];
  const float* vgw  = (const float*)d_in[7];
  const float* ascl = (const float*)d_in[8];
  const int*   docs = (const int*)d_in[9];
  float* out = (float*)d_out;

  const size_t BT = (size_t)B_ * T_;  // 4096
  float* cur = (float*)d_ws;
  bf16_t* x_bf = (bf16_t*)cur;        cur += BT * D_ / 2;
  bf16_t* wq_bf = (bf16_t*)cur;       cur += (size_t)3 * D_ * D_ / 2;
  bf16_t* wo_bf = (bf16_t*)cur;       cur += (size_t)D_ * D_ / 2;
  bf16_t* wg_bf = (bf16_t*)cur;       cur += (size_t)2 * H_ * D_ / 2;
  bf16_t* qkv_b = (bf16_t*)cur;       cur += BT * 3 * D_ / 2;
  bf16_t* q_bf = (bf16_t*)cur;        cur += BT * D_ / 2;
  bf16_t* k_bf = (bf16_t*)cur;        cur += BT * D_ / 2;
  bf16_t* v_bf = (bf16_t*)cur;        cur += BT * D_ / 2;
  bf16_t* y_bf = (bf16_t*)cur;        cur += BT * D_ / 2;
  float* attn_gate = cur;             cur += BT * H_;

  // 0) single fused cast: x, wq, wo, wg (gate weights)
  cast_all<<<(NX4_ + NQ4_ + 2 * NG4_) / 256, 256, 0, stream>>>(
      x, qkvo, agw, vgw, x_bf, wq_bf, wo_bf, wg_bf);

  // 1) QKV projection (bf16 MFMA, bf16 out) — 768 blocks = 3.0/CU, no tail
  gemm_bf16<<<dim3(3 * D_ / 128, BT / 128), 256, 0, stream>>>(
      x_bf, wq_bf, qkv_b, (int)BT, 3 * D_, D_, lam, 0, 1);

  // 2) gates + rmsnorm + rotary + v-augment -> bf16 q/k/v (B,H,T,HD)
  post_kernel<<<(int)BT, 256, 0, stream>>>(
      x, qkv_b, ve, cosb, sinb, wg_bf, q_bf, k_bf, v_bf, attn_gate);

  // 3) MFMA flash attention (doc-block-diagonal skip; key-offset fused)
  attn_mfma<<<dim3(T_ / 64, B_ * H_), 256, 0, stream>>>(
      q_bf, k_bf, v_bf, attn_gate, docs, ascl, y_bf);

  // 4) output projection (bf16 MFMA, f32 out) — 256 blocks = 1.0/CU
  gemm_bf16<<<dim3(D_ / 128, BT / 128), 256, 0, stream>>>(
      y_bf, wo_bf, out, (int)BT, D_, D_, lam, 1, 0);
}

// Round 10
// 131.346 us; speedup vs baseline: 1.2261x; 1.0258x over previous
//
#include <hip/hip_runtime.h>
#include <math.h>

#define B_ 2
#define T_ 2048
#define D_ 1024
#define H_ 16
#define HD_ 64
#define EPS_ 1.1920929e-07f
#define VE_SCALE_ 2.0f

#define NX4_ (B_ * T_ * D_ / 4)          // 1048576
#define NS4_ (3 * D_ * D_ / 4)           // 786432
#define NQ4_ (4 * D_ * D_ / 4)           // 1048576
#define NG4_ (H_ * D_ / 4)               // 4096

typedef __bf16 bf16_t;
typedef __bf16 bf16x4 __attribute__((ext_vector_type(4)));
typedef __bf16 bf16x8 __attribute__((ext_vector_type(8)));
typedef float f32x4 __attribute__((ext_vector_type(4)));

__device__ const f32x4 F4ZERO = {0.f, 0.f, 0.f, 0.f};

typedef __attribute__((address_space(1))) const void gvoid_t;
typedef __attribute__((address_space(3))) void lvoid_t;

__device__ __forceinline__ void gl_lds16(const bf16_t* g, bf16_t* l) {
  // async global->LDS, 16B/lane; LDS dest = wave-uniform base + lane*16
  __builtin_amdgcn_global_load_lds((gvoid_t*)g, (lvoid_t*)l, 16, 0, 0);
}

// ------------- single fused f32->bf16 cast ---------------------------------
// regions: x->x_bf, qkvo rows [0,3072)->wq, [3072,4096)->wo, agw/vgw->wg
__global__ __launch_bounds__(256) void cast_all(
    const float* __restrict__ x, const float* __restrict__ qkvo,
    const float* __restrict__ agw, const float* __restrict__ vgw,
    bf16_t* __restrict__ x_bf, bf16_t* __restrict__ wq,
    bf16_t* __restrict__ wo, bf16_t* __restrict__ wg)
{
  const int i = blockIdx.x * 256 + threadIdx.x;
  const float4* src;
  bf16x4* dst;
  if (i < NX4_) {
    src = (const float4*)x + i;
    dst = (bf16x4*)x_bf + i;
  } else if (i < NX4_ + NS4_) {
    const int j = i - NX4_;
    src = (const float4*)qkvo + j;
    dst = (bf16x4*)wq + j;
  } else if (i < NX4_ + NQ4_) {
    const int j = i - NX4_;
    src = (const float4*)qkvo + j;
    dst = (bf16x4*)wo + (j - NS4_);
  } else if (i < NX4_ + NQ4_ + NG4_) {
    const int j = i - NX4_ - NQ4_;
    src = (const float4*)agw + j;
    dst = (bf16x4*)wg + j;
  } else {
    const int j = i - NX4_ - NQ4_ - NG4_;
    src = (const float4*)vgw + j;
    dst = (bf16x4*)wg + NG4_ + j;
  }
  const float4 v = *src;
  bf16x4 o = {(bf16_t)v.x, (bf16_t)v.y, (bf16_t)v.z, (bf16_t)v.w};
  *dst = o;
}

// ------- bf16 MFMA GEMM: 128x128 tile, BK=32, 2-phase LDS double-buffer ----
// C = scale * A @ W^T. 4 waves (2x2 of 64x64), global_load_lds width-16.
// T3-minimum pipeline: issue next K-tile's staging BEFORE this tile's
// ds_read+MFMA; the single __syncthreads (vmcnt0+lgkmcnt0+barrier) lands
// after compute, so prefetch latency hides under the MFMA phase.
// Grid must be k*256 blocks (tail-free; r4-r8 A/B: 32-block tail = +25us).
__global__ __launch_bounds__(256) void gemm_bf16(
    const bf16_t* __restrict__ A, const bf16_t* __restrict__ W,
    void* __restrict__ Cout, int M, int N, int K,
    const float* __restrict__ lam, int li, int out_bf)
{
  const float scale = lam[li];
  __shared__ bf16_t As[2][128][32];
  __shared__ bf16_t Bs[2][128][32];
  const int tid = threadIdx.x;
  const int lane = tid & 63, w = tid >> 6;
  const int lr = lane & 15, lg = lane >> 4;
  const int wr = w >> 1, wc = w & 1;

  const int nwg = gridDim.x * gridDim.y;
  int bid = blockIdx.y * gridDim.x + blockIdx.x;
  bid = (bid & 7) * (nwg >> 3) + (bid >> 3);
  const int row0 = (bid / gridDim.x) * 128;
  const int col0 = (bid % gridDim.x) * 128;

  // staging: wave w covers tile rows [w*32, +32); each gl_lds covers 16 rows
  const int srow = w * 32 + (lane >> 2);
  const int scol = (lane & 3) * 8;
  const bf16_t* Ag = A + (size_t)(row0 + srow) * K + scol;
  const bf16_t* Wg = W + (size_t)(col0 + srow) * K + scol;
  const size_t r16 = (size_t)16 * K;

  f32x4 acc[4][4];
#pragma unroll
  for (int i = 0; i < 4; ++i)
#pragma unroll
    for (int j = 0; j < 4; ++j) acc[i][j] = F4ZERO;

#define STAGE_(bi, kk)                                    \
  do {                                                    \
    gl_lds16(Ag + (kk), &As[bi][w * 32][0]);              \
    gl_lds16(Ag + r16 + (kk), &As[bi][w * 32 + 16][0]);   \
    gl_lds16(Wg + (kk), &Bs[bi][w * 32][0]);              \
    gl_lds16(Wg + r16 + (kk), &Bs[bi][w * 32 + 16][0]);   \
  } while (0)

#define COMPUTE_(bi)                                                     \
  do {                                                                   \
    bf16x8 af[4], bfr[4];                                                \
    _Pragma("unroll")                                                    \
    for (int fm = 0; fm < 4; ++fm)                                       \
      af[fm] = *(const bf16x8*)&As[bi][wr * 64 + fm * 16 + lr][lg * 8];  \
    _Pragma("unroll")                                                    \
    for (int fn = 0; fn < 4; ++fn)                                       \
      bfr[fn] = *(const bf16x8*)&Bs[bi][wc * 64 + fn * 16 + lr][lg * 8]; \
    _Pragma("unroll")                                                    \
    for (int fm = 0; fm < 4; ++fm)                                       \
      _Pragma("unroll")                                                  \
      for (int fn = 0; fn < 4; ++fn)                                     \
        acc[fm][fn] = __builtin_amdgcn_mfma_f32_16x16x32_bf16(           \
            af[fm], bfr[fn], acc[fm][fn], 0, 0, 0);                      \
  } while (0)

  // prologue: fill buf0
  STAGE_(0, 0);
  __syncthreads();
  // main loop: manual 2x unroll keeps buffer indices compile-time
  for (int k0 = 0; k0 + 64 <= K; k0 += 64) {
    STAGE_(1, k0 + 32);     // prefetch (latency hides under COMPUTE_(0))
    COMPUTE_(0);
    __syncthreads();        // drains vmcnt(0): buf1 ready; all reads of buf0 done
    if (k0 + 64 < K) STAGE_(0, k0 + 64);
    COMPUTE_(1);
    __syncthreads();
  }
#undef STAGE_
#undef COMPUTE_

  // epilogue: C/D layout col=lane&15, row=(lane>>4)*4+reg  [m89]
#pragma unroll
  for (int fm = 0; fm < 4; ++fm)
#pragma unroll
    for (int fn = 0; fn < 4; ++fn)
#pragma unroll
      for (int r = 0; r < 4; ++r) {
        const int row = row0 + wr * 64 + fm * 16 + lg * 4 + r;
        const int col = col0 + wc * 64 + fn * 16 + lr;
        const float v = acc[fm][fn][r] * scale;
        if (out_bf) ((bf16_t*)Cout)[(size_t)row * N + col] = (bf16_t)v;
        else        ((float*)Cout)[(size_t)row * N + col] = v;
      }
}

// -------- post: gates (from LDS-staged x) + rmsnorm + rotary + v-augment ---
// One block per (b,t). x row staged once in LDS; 32 gate dot-products
// (weights bf16, 64KB resident in L2 across blocks); then each wave handles
// 4 heads: rmsnorm+rotary q/k, v += ve_gate*ve. Outputs bf16 (B,H,T,HD).
__global__ __launch_bounds__(256) void post_kernel(
    const float* __restrict__ x, const bf16_t* __restrict__ qkv_b,
    const float* __restrict__ ve, const float* __restrict__ cosb,
    const float* __restrict__ sinb, const bf16_t* __restrict__ wg,
    bf16_t* __restrict__ q_bf, bf16_t* __restrict__ k_bf,
    bf16_t* __restrict__ v_bf, float* __restrict__ attn_gate)
{
  const int bt = blockIdx.x;           // 0..B*T-1
  const int b = bt >> 11, t = bt & (T_ - 1);
  const int tid = threadIdx.x;
  __shared__ float xs[D_];
  __shared__ float gsc[32];

  *(float4*)&xs[tid * 4] = ((const float4*)(x + (size_t)bt * D_))[tid];
  __syncthreads();

  // gate dots: output g = tid>>3 (0..31: 0-15 attn, 16-31 ve), segment c=tid&7
  {
    const int g = tid >> 3, cg = tid & 7;
    const bf16x8* wrow = (const bf16x8*)(wg + (size_t)g * D_);
    float sum = 0.f;
#pragma unroll
    for (int j = 0; j < 16; ++j) {
      const bf16x8 w8 = wrow[cg + 8 * j];
      const float* xp = &xs[(cg + 8 * j) * 8];
#pragma unroll
      for (int e = 0; e < 8; ++e) sum = fmaf((float)w8[e], xp[e], sum);
    }
    sum += __shfl_xor(sum, 1);
    sum += __shfl_xor(sum, 2);
    sum += __shfl_xor(sum, 4);
    if (cg == 0)
      gsc[g] = (g < 16 ? 1.f : VE_SCALE_) / (1.f + __expf(-sum));
  }
  __syncthreads();

  // per-head work: wave w handles heads w, w+4, w+8, w+12
  const int w = tid >> 6, lane = tid & 63;
  const float c = cosb[t * 32 + (lane & 31)];
  const float s = sinb[t * 32 + (lane & 31)];
  const size_t row = (size_t)bt * 3072;
#pragma unroll
  for (int i = 0; i < 4; ++i) {
    const int h = w + i * 4;
    const float qraw = (float)qkv_b[row + h * HD_ + lane];
    const float kraw = (float)qkv_b[row + D_ + h * HD_ + lane];
    const float vraw = (float)qkv_b[row + 2 * D_ + h * HD_ + lane];
    float ssq = qraw * qraw, ssk = kraw * kraw;
#pragma unroll
    for (int off = 32; off > 0; off >>= 1) {
      ssq += __shfl_xor(ssq, off);
      ssk += __shfl_xor(ssk, off);
    }
    const float qn = qraw * rsqrtf(ssq * (1.f / 64.f) + EPS_);
    const float kn = kraw * rsqrtf(ssk * (1.f / 64.f) + EPS_);
    const float qpartner = __shfl_xor(qn, 32);
    const float kpartner = __shfl_xor(kn, 32);
    const float qo = (lane < 32) ? fmaf(qn, c, qpartner * s)
                                 : fmaf(qn, c, -qpartner * s);
    const float ko = (lane < 32) ? fmaf(kn, c, kpartner * s)
                                 : fmaf(kn, c, -kpartner * s);
    const size_t oidx = ((size_t)(b * H_ + h) * T_ + t) * HD_ + lane;
    q_bf[oidx] = (bf16_t)qo;
    k_bf[oidx] = (bf16_t)ko;
    const float vv = fmaf(gsc[16 + h], ve[(size_t)bt * D_ + h * HD_ + lane], vraw);
    v_bf[oidx] = (bf16_t)vv;
    if (lane == 0) attn_gate[bt * H_ + h] = gsc[h];
  }
}

// ---------------- MFMA flash attention, doc-block-diagonal ----------------
// Grid (32 q-tiles, 32 bh); block = 4 waves, wave w owns q-rows w*16..+16.
// docs sorted => q-tile qt only attends kt in [ktlo, qt].
__global__ __launch_bounds__(256) void attn_mfma(
    const bf16_t* __restrict__ q_buf, const bf16_t* __restrict__ k_tmp,
    const bf16_t* __restrict__ v_buf, const float* __restrict__ attn_gate,
    const int* __restrict__ docs, const float* __restrict__ scale_ptr,
    bf16_t* __restrict__ y_buf)
{
  const int qt = blockIdx.x, bh = blockIdx.y;
  const int b = bh >> 4, h = bh & 15;
  const int tid = threadIdx.x;
  const int w = tid >> 6, lane = tid & 63;
  const int lr = lane & 15, lg = lane >> 4;
  const float scale = scale_ptr[0];
  __shared__ bf16_t Ks[64][72];
  __shared__ bf16_t Vt[64][72];
  __shared__ bf16_t Ps[64][72];
  __shared__ int dk[64];

  // doc-range lower bound for this q-tile (docs sorted)
  const int dlo = docs[qt * 64];
  const unsigned long long bal =
      __ballot((lane <= qt) && (docs[lane * 64 + 63] >= dlo));
  const int ktlo = __ffsll(bal) - 1;

  // Q a-frags hoisted (A-frag: row = lane&15, k = (lane>>4)*8+j)
  const bf16_t* qp = q_buf + ((size_t)bh * T_ + qt * 64 + w * 16 + lr) * HD_;
  const bf16x8 aq0 = *(const bf16x8*)(qp + lg * 8);
  const bf16x8 aq1 = *(const bf16x8*)(qp + 32 + lg * 8);
  int qpos_r[4], docq_r[4];
#pragma unroll
  for (int r = 0; r < 4; ++r) {
    qpos_r[r] = qt * 64 + w * 16 + lg * 4 + r;
    docq_r[r] = docs[qpos_r[r]];
  }
  f32x4 acc[4];
#pragma unroll
  for (int fn = 0; fn < 4; ++fn) acc[fn] = F4ZERO;
  float m[4] = {-1e30f, -1e30f, -1e30f, -1e30f};
  float l[4] = {0.f, 0.f, 0.f, 0.f};

#pragma unroll 1
  for (int kt = ktlo; kt <= qt; ++kt) {
    __syncthreads();
#pragma unroll
    for (int i = 0; i < 2; ++i) {
      const int idx = i * 256 + tid;
      // K staging (fused key-offset: channels [16,32)|[48,64) from t-1)
      const int krow = idx >> 3;
      const int c8 = (idx & 7) << 3;
      const int gk = kt * 64 + krow;
      const int gks = (((c8 & 16) != 0) && gk > 0) ? gk - 1 : gk;
      *(bf16x8*)&Ks[krow][c8] =
          *(const bf16x8*)(k_tmp + ((size_t)bh * T_ + gks) * HD_ + c8);
      // V transpose staging
      const int kpos = idx & 63;
      const int d0 = (idx >> 6) << 3;
      const bf16x8 vv =
          *(const bf16x8*)(v_buf + ((size_t)bh * T_ + kt * 64 + kpos) * HD_ + d0);
#pragma unroll
      for (int j = 0; j < 8; ++j) Vt[d0 + j][kpos] = vv[j];
    }
    if (tid < 64) dk[tid] = docs[kt * 64 + tid];
    __syncthreads();

    // S = Q K^T  (B-frag: col = lane&15 = kpos, k = d contiguous)
    f32x4 s[4];
#pragma unroll
    for (int fn = 0; fn < 4; ++fn) {
      const bf16x8 bk0 = *(const bf16x8*)&Ks[fn * 16 + lr][lg * 8];
      const bf16x8 bk1 = *(const bf16x8*)&Ks[fn * 16 + lr][32 + lg * 8];
      f32x4 z = F4ZERO;
      z = __builtin_amdgcn_mfma_f32_16x16x32_bf16(aq0, bk0, z, 0, 0, 0);
      s[fn] = __builtin_amdgcn_mfma_f32_16x16x32_bf16(aq1, bk1, z, 0, 0, 0);
    }
    // mask + scale (lane holds rows lg*4+r, col fn*16+lr of the 64x64 S)
    const bool strict = (kt < qt);
#pragma unroll
    for (int fn = 0; fn < 4; ++fn) {
      const int kd = dk[fn * 16 + lr];
      const int kp = kt * 64 + fn * 16 + lr;
#pragma unroll
      for (int r = 0; r < 4; ++r) {
        const bool valid = (kd == docq_r[r]) && (strict || kp <= qpos_r[r]);
        s[fn][r] = valid ? s[fn][r] * scale : -3.0e38f;
      }
    }
    // online softmax (row reduce across 16-lane col group) + P write
#pragma unroll
    for (int r = 0; r < 4; ++r) {
      float cm = fmaxf(fmaxf(s[0][r], s[1][r]), fmaxf(s[2][r], s[3][r]));
      cm = fmaxf(cm, __shfl_xor(cm, 1));
      cm = fmaxf(cm, __shfl_xor(cm, 2));
      cm = fmaxf(cm, __shfl_xor(cm, 4));
      cm = fmaxf(cm, __shfl_xor(cm, 8));
      const float mn = fmaxf(m[r], cm);
      const float sc = __expf(m[r] - mn);
      m[r] = mn;
      const float p0 = __expf(s[0][r] - mn);
      const float p1 = __expf(s[1][r] - mn);
      const float p2 = __expf(s[2][r] - mn);
      const float p3 = __expf(s[3][r] - mn);
      float ps = (p0 + p1) + (p2 + p3);
      ps += __shfl_xor(ps, 1);
      ps += __shfl_xor(ps, 2);
      ps += __shfl_xor(ps, 4);
      ps += __shfl_xor(ps, 8);
      l[r] = l[r] * sc + ps;
      acc[0][r] *= sc; acc[1][r] *= sc; acc[2][r] *= sc; acc[3][r] *= sc;
      const int prow = w * 16 + lg * 4 + r;
      Ps[prow][0 + lr]  = (bf16_t)p0;
      Ps[prow][16 + lr] = (bf16_t)p1;
      Ps[prow][32 + lr] = (bf16_t)p2;
      Ps[prow][48 + lr] = (bf16_t)p3;
    }
    // PV: A = P rows (wave-private LDS slice), B = Vt rows (col = d)
    const bf16x8 ap0 = *(const bf16x8*)&Ps[w * 16 + lr][lg * 8];
    const bf16x8 ap1 = *(const bf16x8*)&Ps[w * 16 + lr][32 + lg * 8];
#pragma unroll
    for (int fn = 0; fn < 4; ++fn) {
      const bf16x8 bv0 = *(const bf16x8*)&Vt[fn * 16 + lr][lg * 8];
      const bf16x8 bv1 = *(const bf16x8*)&Vt[fn * 16 + lr][32 + lg * 8];
      acc[fn] = __builtin_amdgcn_mfma_f32_16x16x32_bf16(ap0, bv0, acc[fn], 0, 0, 0);
      acc[fn] = __builtin_amdgcn_mfma_f32_16x16x32_bf16(ap1, bv1, acc[fn], 0, 0, 0);
    }
  }
  // epilogue: gate & normalize, write bf16 y (B,T,D)
#pragma unroll
  for (int r = 0; r < 4; ++r) {
    const float inv = attn_gate[(size_t)(b * T_ + qpos_r[r]) * H_ + h] / l[r];
#pragma unroll
    for (int fn = 0; fn < 4; ++fn)
      y_buf[(size_t)(b * T_ + qpos_r[r]) * D_ + h * HD_ + fn * 16 + lr] =
          (bf16_t)(acc[fn][r] * inv);
  }
}

extern "C" void kernel_launch(void* const* d_in, const int* in_sizes, int n_in,
                              void* d_out, int out_size, void* d_ws, size_t ws_size,
                              hipStream_t stream) {
  const float* x    = (const float*)d_in[0];
  const float* ve   = (const float*)d_in[1];
  const float* lam  = (const float*)d_in[2];
  const float* cosb = (const float*)d_in[3];
  const float* sinb = (const float*)d_in[4];
  const float* qkvo = (const float*)d_in[5];
  const float* agw  = (const float*)d_in[6];
  const float* vgw  = (const float*)d_in[7];
  const float* ascl = (const float*)d_in[8];
  const int*   docs = (const int*)d_in[9];
  float* out = (float*)d_out;

  const size_t BT = (size_t)B_ * T_;  // 4096
  float* cur = (float*)d_ws;
  bf16_t* x_bf = (bf16_t*)cur;        cur += BT * D_ / 2;
  bf16_t* wq_bf = (bf16_t*)cur;       cur += (size_t)3 * D_ * D_ / 2;
  bf16_t* wo_bf = (bf16_t*)cur;       cur += (size_t)D_ * D_ / 2;
  bf16_t* wg_bf = (bf16_t*)cur;       cur += (size_t)2 * H_ * D_ / 2;
  bf16_t* qkv_b = (bf16_t*)cur;       cur += BT * 3 * D_ / 2;
  bf16_t* q_bf = (bf16_t*)cur;        cur += BT * D_ / 2;
  bf16_t* k_bf = (bf16_t*)cur;        cur += BT * D_ / 2;
  bf16_t* v_bf = (bf16_t*)cur;        cur += BT * D_ / 2;
  bf16_t* y_bf = (bf16_t*)cur;        cur += BT * D_ / 2;
  float* attn_gate = cur;             cur += BT * H_;

  // 0) single fused cast: x, wq, wo, wg (gate weights)
  cast_all<<<(NX4_ + NQ4_ + 2 * NG4_) / 256, 256, 0, stream>>>(
      x, qkvo, agw, vgw, x_bf, wq_bf, wo_bf, wg_bf);

  // 1) QKV projection (bf16 MFMA, bf16 out) — 768 blocks = 3.0/CU, no tail
  gemm_bf16<<<dim3(3 * D_ / 128, BT / 128), 256, 0, stream>>>(
      x_bf, wq_bf, qkv_b, (int)BT, 3 * D_, D_, lam, 0, 1);

  // 2) gates + rmsnorm + rotary + v-augment -> bf16 q/k/v (B,H,T,HD)
  post_kernel<<<(int)BT, 256, 0, stream>>>(
      x, qkv_b, ve, cosb, sinb, wg_bf, q_bf, k_bf, v_bf, attn_gate);

  // 3) MFMA flash attention (doc-block-diagonal skip; key-offset fused)
  attn_mfma<<<dim3(T_ / 64, B_ * H_), 256, 0, stream>>>(
      q_bf, k_bf, v_bf, attn_gate, docs, ascl, y_bf);

  // 4) output projection (bf16 MFMA, f32 out) — 256 blocks = 1.0/CU
  gemm_bf16<<<dim3(D_ / 128, BT / 128), 256, 0, stream>>>(
      y_bf, wo_bf, out, (int)BT, D_, D_, lam, 1, 0);
}